// Round 18
// baseline (3582.980 us; speedup 1.0000x reference)
//
#include <hip/hip_runtime.h>
#include <hip/hip_bf16.h>

#define EMB 1024
#define NH 16
#define HD 64
#define BS 4
#define SEQ 2048
#define MROWS (BS*SEQ)   // 8192

typedef __attribute__((ext_vector_type(8))) short short8;
typedef __hip_bfloat16 bf16;

__device__ __forceinline__ float bf2f(unsigned short u) {
  return __builtin_bit_cast(float, ((unsigned)u) << 16);
}
__device__ __forceinline__ unsigned short f2bf_rne(float x) {
  unsigned u = __builtin_bit_cast(unsigned, x);
  u += 0x7FFFu + ((u >> 16) & 1u);
  return (unsigned short)(u >> 16);
}

// ---------------------------------------------------------------------------
// Pure-VALU f32 GEMM (torch Linear): out = A @ W.T + bias.
// A f32 (ABF16=0) or bf16 (ABF16=1); W, bias f32.
// MODE 0: bf16 out at [((b*NH+h)*SEQ+s)*HD+d]   ([B,H,S,D] proper split)
// MODE 1: FLOAT32 out at [m*EMB+n]              (row-major final output)
// ---------------------------------------------------------------------------
template<int MODE, bool ABF16>
__global__ __launch_bounds__(256)
void gemm_f32(const void* __restrict__ Ap, const float* __restrict__ W,
              const float* __restrict__ bias, void* __restrict__ out)
{
  __shared__ float As[64][17];
  __shared__ float Ws[64][17];
  const int tid = threadIdx.x;
  const int tx = tid & 15, ty = tid >> 4;
  const int bn = blockIdx.x * 64, bm = blockIdx.y * 64;
  const int srow = tid >> 2, skc = (tid & 3) * 4;

  float acc[4][4] = {};
  for (int k0 = 0; k0 < EMB; k0 += 16) {
    __syncthreads();
    if (ABF16) {
      const unsigned short* Ab = (const unsigned short*)Ap;
      ushort4 v = *(const ushort4*)(Ab + (size_t)(bm + srow) * EMB + k0 + skc);
      As[srow][skc+0] = bf2f(v.x); As[srow][skc+1] = bf2f(v.y);
      As[srow][skc+2] = bf2f(v.z); As[srow][skc+3] = bf2f(v.w);
    } else {
      const float* Af = (const float*)Ap;
      float4 v = *(const float4*)(Af + (size_t)(bm + srow) * EMB + k0 + skc);
      As[srow][skc+0] = v.x; As[srow][skc+1] = v.y;
      As[srow][skc+2] = v.z; As[srow][skc+3] = v.w;
    }
    {
      float4 v = *(const float4*)(W + (size_t)(bn + srow) * EMB + k0 + skc);
      Ws[srow][skc+0] = v.x; Ws[srow][skc+1] = v.y;
      Ws[srow][skc+2] = v.z; Ws[srow][skc+3] = v.w;
    }
    __syncthreads();
    #pragma unroll
    for (int k = 0; k < 16; ++k) {
      float a4[4], w4[4];
      #pragma unroll
      for (int i = 0; i < 4; ++i) a4[i] = As[ty*4+i][k];
      #pragma unroll
      for (int j = 0; j < 4; ++j) w4[j] = Ws[tx*4+j][k];
      #pragma unroll
      for (int i = 0; i < 4; ++i)
        #pragma unroll
        for (int j = 0; j < 4; ++j)
          acc[i][j] += a4[i] * w4[j];
    }
  }

  #pragma unroll
  for (int i = 0; i < 4; ++i) {
    const int m = bm + ty*4 + i;
    const int b = m >> 11, s = m & 2047;
    #pragma unroll
    for (int j = 0; j < 4; ++j) {
      const int n = bn + tx*4 + j;
      const float val = acc[i][j] + bias[n];
      if (MODE == 0) {
        const int h = n >> 6, d = n & 63;
        ((unsigned short*)out)[((size_t)((b*NH + h)*SEQ + s))*HD + d] = f2bf_rne(val);
      } else {
        ((float*)out)[(size_t)m*EMB + n] = val;   // FLOAT32 final output
      }
    }
  }
}

// ---------------------------------------------------------------------------
// Attention (verified scaffold): faithful reference math. f32 math on bf16
// Q/K/V [B*H][S][D]; canonical merge X[b][s][h*64+d] (bf16).
// 4-lane group owns one q-row; lane part lp owns d-slice lp*16..+15.
// ---------------------------------------------------------------------------
__global__ __launch_bounds__(256)
void attn_simple(const bf16* __restrict__ Q, const bf16* __restrict__ K,
                 const bf16* __restrict__ V, bf16* __restrict__ X)
{
  const int tid = threadIdx.x;
  const int lp = tid & 3;
  const int qr = tid >> 2;
  const int qt = blockIdx.x, bh = blockIdx.y;
  const int qrow = qt*64 + qr;

  const unsigned short* Qb = (const unsigned short*)Q + ((size_t)bh*SEQ + qrow)*HD + lp*16;
  const unsigned short* Kb = (const unsigned short*)K + (size_t)bh*SEQ*HD + lp*16;
  const unsigned short* Vb = (const unsigned short*)V + (size_t)bh*SEQ*HD + lp*16;

  float q[16];
  {
    short8 a = *(const short8*)(Qb);
    short8 b = *(const short8*)(Qb + 8);
    #pragma unroll
    for (int j = 0; j < 8; ++j) { q[j] = bf2f((unsigned short)a[j]); q[j+8] = bf2f((unsigned short)b[j]); }
  }

  float o[16] = {};
  float mrun = -3.0e38f, lrun = 0.f;

  for (int k = 0; k < SEQ; ++k) {
    const unsigned short* kr = Kb + (size_t)k*HD;
    short8 ka = *(const short8*)(kr);
    short8 kb2 = *(const short8*)(kr + 8);
    float s = 0.f;
    #pragma unroll
    for (int j = 0; j < 8; ++j) {
      s += q[j]   * bf2f((unsigned short)ka[j]);
      s += q[j+8] * bf2f((unsigned short)kb2[j]);
    }
    s += __shfl_xor(s, 1, 64);
    s += __shfl_xor(s, 2, 64);
    s *= 0.125f;                        // 1/sqrt(64)
    if (s > mrun) {
      const float f = __expf(mrun - s);
      lrun *= f;
      #pragma unroll
      for (int j = 0; j < 16; ++j) o[j] *= f;
      mrun = s;
    }
    const float p = __expf(s - mrun);
    lrun += p;
    const unsigned short* vr = Vb + (size_t)k*HD;
    short8 va = *(const short8*)(vr);
    short8 vb2 = *(const short8*)(vr + 8);
    #pragma unroll
    for (int j = 0; j < 8; ++j) {
      o[j]   += p * bf2f((unsigned short)va[j]);
      o[j+8] += p * bf2f((unsigned short)vb2[j]);
    }
  }

  const int b = bh >> 4, h = bh & 15;
  unsigned short* Xo = (unsigned short*)X + ((size_t)(b*SEQ + qrow))*EMB + h*HD + lp*16;
  const float inv = 1.f / lrun;
  #pragma unroll
  for (int j = 0; j < 16; ++j) Xo[j] = f2bf_rne(o[j] * inv);
}

// ---------------------------------------------------------------------------
extern "C" void kernel_launch(void* const* d_in, const int* in_sizes, int n_in,
                              void* d_out, int out_size, void* d_ws, size_t ws_size,
                              hipStream_t stream)
{
  // Inputs RNG-PROVEN literal (R13): exactly as displayed in setup_inputs.
  const float* q  = (const float*)d_in[0];
  const float* k  = (const float*)d_in[1];
  const float* v  = (const float*)d_in[2];
  const float* Wq = (const float*)d_in[3];
  const float* bq = (const float*)d_in[4];
  const float* Wk = (const float*)d_in[5];
  const float* bk = (const float*)d_in[6];
  const float* Wv = (const float*)d_in[7];
  const float* bv = (const float*)d_in[8];
  const float* Wo = (const float*)d_in[9];
  const float* bo = (const float*)d_in[10];

  // ws: Q,K,V [B,H,S,D] bf16 + X [B,S,E] bf16 = 67 MB
  bf16* Qw = (bf16*)d_ws;
  bf16* Kw = Qw + (size_t)MROWS*EMB;
  bf16* Vw = Kw + (size_t)MROWS*EMB;
  bf16* Xw = Vw + (size_t)MROWS*EMB;

  dim3 gp(EMB/64, MROWS/64);   // (16, 128)
  gemm_f32<0, false><<<gp, 256, 0, stream>>>(q, Wq, bq, Qw);
  gemm_f32<0, false><<<gp, 256, 0, stream>>>(k, Wk, bk, Kw);
  gemm_f32<0, false><<<gp, 256, 0, stream>>>(v, Wv, bv, Vw);
  attn_simple<<<dim3(SEQ/64, BS*NH), 256, 0, stream>>>(Qw, Kw, Vw, Xw);
  gemm_f32<1, true><<<gp, 256, 0, stream>>>(Xw, Wo, bo, (float*)d_out);
}

// Round 19
// 333.988 us; speedup vs baseline: 10.7279x; 10.7279x over previous
//
#include <hip/hip_runtime.h>
#include <hip/hip_bf16.h>

#define EMB 1024
#define NH 16
#define HD 64
#define BS 4
#define SEQ 2048
#define MROWS (BS*SEQ)   // 8192

typedef __attribute__((ext_vector_type(8))) short short8;
typedef __attribute__((ext_vector_type(4))) float f32x4;
typedef __hip_bfloat16 bf16;

__device__ __forceinline__ void gload_lds16(const void* g, void* l) {
  __builtin_amdgcn_global_load_lds((const __attribute__((address_space(1))) void*)g,
                                   (__attribute__((address_space(3))) void*)l, 16, 0, 0);
}
__device__ __forceinline__ unsigned short f2bf_rne(float x) {
  unsigned u = __builtin_bit_cast(unsigned, x);
  u += 0x7FFFu + ((u >> 16) & 1u);
  return (unsigned short)(u >> 16);
}

// ---------------------------------------------------------------------------
// Convert all 11 inputs (f32, RNG-proven) to one contiguous bf16 region.
// Element offsets: q 0 | k 8388608 | v 16777216 | Wq 25165824 | Wk +1M |
// Wv +2M | Wo +3M | bq 29360128 | bk | bv | bo  (total 29364224)
// ---------------------------------------------------------------------------
__global__ __launch_bounds__(256)
void convert_all(const float* q, const float* k, const float* v,
                 const float* Wq, const float* bq, const float* Wk, const float* bk,
                 const float* Wv, const float* bv, const float* Wo, const float* bo,
                 bf16* __restrict__ dst)
{
  const int G = 3670528;   // total / 8
  for (int g = blockIdx.x * 256 + threadIdx.x; g < G; g += gridDim.x * 256) {
    const float* src; int lg;
    if      (g < 1048576) { src = q;  lg = g; }
    else if (g < 2097152) { src = k;  lg = g - 1048576; }
    else if (g < 3145728) { src = v;  lg = g - 2097152; }
    else if (g < 3276800) { src = Wq; lg = g - 3145728; }
    else if (g < 3407872) { src = Wk; lg = g - 3276800; }
    else if (g < 3538944) { src = Wv; lg = g - 3407872; }
    else if (g < 3670016) { src = Wo; lg = g - 3538944; }
    else if (g < 3670144) { src = bq; lg = g - 3670016; }
    else if (g < 3670272) { src = bk; lg = g - 3670144; }
    else if (g < 3670400) { src = bv; lg = g - 3670272; }
    else                  { src = bo; lg = g - 3670400; }
    const float4* s4 = ((const float4*)src) + (size_t)lg * 2;
    const float4 a = s4[0], b = s4[1];
    uint4 o;
    o.x = (unsigned)f2bf_rne(a.x) | ((unsigned)f2bf_rne(a.y) << 16);
    o.y = (unsigned)f2bf_rne(a.z) | ((unsigned)f2bf_rne(a.w) << 16);
    o.z = (unsigned)f2bf_rne(b.x) | ((unsigned)f2bf_rne(b.y) << 16);
    o.w = (unsigned)f2bf_rne(b.z) | ((unsigned)f2bf_rne(b.w) << 16);
    ((uint4*)dst)[g] = o;
  }
}

// ---------------------------------------------------------------------------
// MFMA GEMM (verified R2==R4): out = A @ W.T + bias, A/W row-major bf16.
// MODE 0: bf16 out[((b*NH+h)*SEQ+s)*HD+d]   (Q,K -> [B,H,S,D])
// MODE 1: bf16 out[((b*NH+h)*HD+d)*SEQ+s]   (V   -> [B,H,D,S], transposed)
// MODE 2: FLOAT32 out[m*EMB+n]              (final output)
// 128x128 tile, BK=64, 4 waves (2x2 of 64x64), XOR-swizzled LDS via
// pre-swizzled global source + linear global_load_lds dest (rule #21).
// ---------------------------------------------------------------------------
template<int MODE>
__global__ __launch_bounds__(256, 2)
void gemm_bt(const bf16* __restrict__ A, const bf16* __restrict__ W,
             const bf16* __restrict__ bias, void* __restrict__ out)
{
  __shared__ char lds[32768];          // A tile 16KB | B tile 16KB
  const int tid  = threadIdx.x;
  const int lane = tid & 63;
  const int wid  = tid >> 6;
  const int wr   = wid >> 1;
  const int wc   = wid & 1;
  const int bn   = blockIdx.x * 128;
  const int bm   = blockIdx.y * 128;

  f32x4 acc[4][4] = {};
  const char* Ab = (const char*)A;
  const char* Wb = (const char*)W;

  for (int k0 = 0; k0 < EMB; k0 += 64) {
    __syncthreads();
    #pragma unroll
    for (int r = 0; r < 4; ++r) {
      const int o   = r*4096 + wid*1024 + lane*16;
      const int row = o >> 7;
      const int cs  = (o & 127) ^ ((row & 7) << 4);
      gload_lds16(Ab + (size_t)(bm + row)*(EMB*2) + k0*2 + cs, lds + o);
      gload_lds16(Wb + (size_t)(bn + row)*(EMB*2) + k0*2 + cs, lds + 16384 + o);
    }
    __syncthreads();
    #pragma unroll
    for (int ks = 0; ks < 2; ++ks) {
      short8 af[4], bfr[4];
      const int d0 = ks*64 + ((lane >> 4) << 4);
      #pragma unroll
      for (int i = 0; i < 4; ++i) {
        const int ra = wr*64 + i*16 + (lane & 15);
        af[i]  = *(const short8*)(lds + ra*128 + (d0 ^ ((ra & 7) << 4)));
        const int rb = wc*64 + i*16 + (lane & 15);
        bfr[i] = *(const short8*)(lds + 16384 + rb*128 + (d0 ^ ((rb & 7) << 4)));
      }
      #pragma unroll
      for (int i = 0; i < 4; ++i)
        #pragma unroll
        for (int j = 0; j < 4; ++j)
          acc[i][j] = __builtin_amdgcn_mfma_f32_16x16x32_bf16(af[i], bfr[j], acc[i][j], 0, 0, 0);
    }
  }

  // epilogue. C/D layout: col=lane&15, row=(lane>>4)*4+reg
  #pragma unroll
  for (int j = 0; j < 4; ++j) {
    const int n = bn + wc*64 + j*16 + (lane & 15);
    const float bv = __bfloat162float(bias[n]);
    #pragma unroll
    for (int i = 0; i < 4; ++i) {
      const int m0 = bm + wr*64 + i*16 + ((lane >> 4) << 2);
      if (MODE == 1) {
        const int b = m0 >> 11, s = m0 & 2047;
        const int h = n >> 6,  d = n & 63;
        ushort4 vv;
        #pragma unroll
        for (int r = 0; r < 4; ++r)
          ((unsigned short*)&vv)[r] = f2bf_rne(acc[i][j][r] + bv);
        *(ushort4*)((unsigned short*)out + ((size_t)((b*NH + h)*HD + d))*SEQ + s) = vv;
      } else if (MODE == 0) {
        #pragma unroll
        for (int r = 0; r < 4; ++r) {
          const int m = m0 + r;
          const int b = m >> 11, s = m & 2047;
          const int h = n >> 6,  d = n & 63;
          ((unsigned short*)out)[((size_t)((b*NH + h)*SEQ + s))*HD + d] = f2bf_rne(acc[i][j][r] + bv);
        }
      } else {
        #pragma unroll
        for (int r = 0; r < 4; ++r)
          ((float*)out)[(size_t)(m0 + r)*EMB + n] = acc[i][j][r] + bv;
      }
    }
  }
}

// ---------------------------------------------------------------------------
// MFMA flash attention (verified R2==R4). grid = (SEQ/64, BS*NH).
// 4 waves x 16 Q-rows, KVBLK=64, double-buffered K/V prefetch, online
// softmax, P via per-wave swizzled LDS. Q,K: [B*H][S][D]; Vt: [B*H][D][S].
// X: [B][S][EMB] bf16.
// ---------------------------------------------------------------------------
__global__ __launch_bounds__(256, 2)
void attn_fwd(const bf16* __restrict__ Q, const bf16* __restrict__ Kt,
              const bf16* __restrict__ Vt, bf16* __restrict__ X)
{
  // [0,8K) Q | [8K,24K) K dbuf | [24K,40K) V dbuf | [40K,48K) P (2KB/wave)
  __shared__ char lds[49152];
  const int tid  = threadIdx.x;
  const int lane = tid & 63;
  const int wid  = tid >> 6;
  const int qt   = blockIdx.x;
  const int bh   = blockIdx.y;

  const char* Qb = (const char*)Q  + ((size_t)bh*SEQ + qt*64) * (HD*2);
  const char* Kb = (const char*)Kt + ((size_t)bh*SEQ) * (HD*2);
  const char* Vb = (const char*)Vt + ((size_t)bh*HD) * (SEQ*2);

  #pragma unroll
  for (int r = 0; r < 2; ++r) {
    const int o   = r*4096 + wid*1024 + lane*16;
    const int row = o >> 7;
    const int cs  = (o & 127) ^ ((row & 7) << 4);
    gload_lds16(Qb + (size_t)row*(HD*2) + cs, lds + o);
    gload_lds16(Kb + (size_t)row*(HD*2) + cs, lds + 8192 + o);
    gload_lds16(Vb + (size_t)row*(SEQ*2) + cs, lds + 24576 + o);
  }
  __syncthreads();

  short8 qf[2];
  {
    const int q = wid*16 + (lane & 15);
    #pragma unroll
    for (int ks = 0; ks < 2; ++ks) {
      const int d0 = ks*64 + ((lane >> 4) << 4);
      qf[ks] = *(const short8*)(lds + q*128 + (d0 ^ ((q & 7) << 4)));
    }
  }

  f32x4 oacc[4] = {};
  float mrun[4], lrun[4];
  #pragma unroll
  for (int r2 = 0; r2 < 4; ++r2) { mrun[r2] = -__builtin_inff(); lrun[r2] = 0.f; }

  char* PL = lds + 40960 + wid*2048;

  for (int t = 0; t < SEQ/64; ++t) {
    const int cur = t & 1;
    if (t + 1 < SEQ/64) {
      const int nxt = cur ^ 1;
      #pragma unroll
      for (int r = 0; r < 2; ++r) {
        const int o   = r*4096 + wid*1024 + lane*16;
        const int row = o >> 7;
        const int cs  = (o & 127) ^ ((row & 7) << 4);
        gload_lds16(Kb + (size_t)((t+1)*64 + row)*(HD*2) + cs, lds + 8192 + nxt*8192 + o);
        gload_lds16(Vb + (size_t)row*(SEQ*2) + (size_t)(t+1)*128 + cs, lds + 24576 + nxt*8192 + o);
      }
    }
    const char* KL = lds + 8192  + cur*8192;
    const char* VL = lds + 24576 + cur*8192;

    // S = Q K^T
    f32x4 s[4] = {};
    #pragma unroll
    for (int ks = 0; ks < 2; ++ks) {
      const int d0 = ks*64 + ((lane >> 4) << 4);
      #pragma unroll
      for (int cg = 0; cg < 4; ++cg) {
        const int key = cg*16 + (lane & 15);
        short8 kf = *(const short8*)(KL + key*128 + (d0 ^ ((key & 7) << 4)));
        s[cg] = __builtin_amdgcn_mfma_f32_16x16x32_bf16(qf[ks], kf, s[cg], 0, 0, 0);
      }
    }
    #pragma unroll
    for (int cg = 0; cg < 4; ++cg) s[cg] *= 0.125f;

    // online softmax (row = (lane>>4)*4+r2; 16 col-lanes reduce)
    float alpha[4];
    #pragma unroll
    for (int r2 = 0; r2 < 4; ++r2) {
      float mt = fmaxf(fmaxf(s[0][r2], s[1][r2]), fmaxf(s[2][r2], s[3][r2]));
      #pragma unroll
      for (int off = 1; off < 16; off <<= 1)
        mt = fmaxf(mt, __shfl_xor(mt, off, 64));
      const float mn = fmaxf(mrun[r2], mt);
      alpha[r2] = __expf(mrun[r2] - mn);
      mrun[r2] = mn;
      float ps = 0.f;
      #pragma unroll
      for (int cg = 0; cg < 4; ++cg) {
        const float p = __expf(s[cg][r2] - mn);
        s[cg][r2] = p;
        ps += p;
      }
      #pragma unroll
      for (int off = 1; off < 16; off <<= 1)
        ps += __shfl_xor(ps, off, 64);
      lrun[r2] = lrun[r2]*alpha[r2] + ps;
    }

    // write P (bf16, swizzled, per-wave) + rescale O
    #pragma unroll
    for (int r2 = 0; r2 < 4; ++r2) {
      const int rr = ((lane >> 4) << 2) + r2;
      #pragma unroll
      for (int cg = 0; cg < 4; ++cg) {
        const int c2 = (cg*16 + (lane & 15)) * 2;
        *(unsigned short*)(PL + rr*128 + (c2 ^ ((rr & 7) << 4))) = f2bf_rne(s[cg][r2]);
      }
      oacc[0][r2] *= alpha[r2]; oacc[1][r2] *= alpha[r2];
      oacc[2][r2] *= alpha[r2]; oacc[3][r2] *= alpha[r2];
    }

    // O += P V
    #pragma unroll
    for (int ks = 0; ks < 2; ++ks) {
      const int d0 = ks*64 + ((lane >> 4) << 4);
      const int qrow = lane & 15;
      short8 pa = *(const short8*)(PL + qrow*128 + (d0 ^ ((qrow & 7) << 4)));
      #pragma unroll
      for (int dg = 0; dg < 4; ++dg) {
        const int dd = dg*16 + (lane & 15);
        short8 vf = *(const short8*)(VL + dd*128 + (d0 ^ ((dd & 7) << 4)));
        oacc[dg] = __builtin_amdgcn_mfma_f32_16x16x32_bf16(pa, vf, oacc[dg], 0, 0, 0);
      }
    }
    __syncthreads();
  }

  // normalize + store X[b][s][h*64+d]
  const int b = bh >> 4, h = bh & 15;
  #pragma unroll
  for (int dg = 0; dg < 4; ++dg) {
    const int d = dg*16 + (lane & 15);
    #pragma unroll
    for (int r2 = 0; r2 < 4; ++r2) {
      const int srow = qt*64 + wid*16 + ((lane >> 4) << 2) + r2;
      ((unsigned short*)X)[((size_t)b*SEQ + srow)*EMB + h*HD + d] =
          f2bf_rne(oacc[dg][r2] / lrun[r2]);
    }
  }
}

// ---------------------------------------------------------------------------
extern "C" void kernel_launch(void* const* d_in, const int* in_sizes, int n_in,
                              void* d_out, int out_size, void* d_ws, size_t ws_size,
                              hipStream_t stream)
{
  const float* q  = (const float*)d_in[0];
  const float* k  = (const float*)d_in[1];
  const float* v  = (const float*)d_in[2];
  const float* Wq = (const float*)d_in[3];
  const float* bq = (const float*)d_in[4];
  const float* Wk = (const float*)d_in[5];
  const float* bk = (const float*)d_in[6];
  const float* Wv = (const float*)d_in[7];
  const float* bv = (const float*)d_in[8];
  const float* Wo = (const float*)d_in[9];
  const float* bo = (const float*)d_in[10];

  bf16* conv = (bf16*)d_ws;
  bf16* cq  = conv;
  bf16* ck  = conv + 8388608;
  bf16* cv  = conv + 16777216;
  bf16* cWq = conv + 25165824;
  bf16* cWk = cWq + 1048576;
  bf16* cWv = cWk + 1048576;
  bf16* cWo = cWv + 1048576;
  bf16* cbq = conv + 29360128;
  bf16* cbk = cbq + 1024;
  bf16* cbv = cbk + 1024;
  bf16* cbo = cbv + 1024;

  bf16* Qw = conv + 29364224;
  bf16* Kw = Qw + (size_t)MROWS*EMB;
  bf16* Vw = Kw + (size_t)MROWS*EMB;
  bf16* Xw = cq;                      // cq dead after Q-projection

  convert_all<<<2048, 256, 0, stream>>>(q, k, v, Wq, bq, Wk, bk, Wv, bv, Wo, bo, conv);

  dim3 gp(EMB/128, MROWS/128);   // (8, 64)
  gemm_bt<0><<<gp, 256, 0, stream>>>(cq, cWq, cbq, Qw);
  gemm_bt<0><<<gp, 256, 0, stream>>>(ck, cWk, cbk, Kw);
  gemm_bt<1><<<gp, 256, 0, stream>>>(cv, cWv, cbv, Vw);
  attn_fwd<<<dim3(SEQ/64, BS*NH), 256, 0, stream>>>(Qw, Kw, Vw, Xw);
  gemm_bt<2><<<gp, 256, 0, stream>>>(Xw, cWo, cbo, (float*)d_out);
}

// Round 20
// 221.005 us; speedup vs baseline: 16.2122x; 1.5112x over previous
//
#include <hip/hip_runtime.h>
#include <hip/hip_bf16.h>

#define EMB 1024
#define NH 16
#define HD 64
#define BS 4
#define SEQ 2048
#define MROWS (BS*SEQ)   // 8192

typedef __attribute__((ext_vector_type(8))) short short8;
typedef __attribute__((ext_vector_type(4))) float f32x4;
typedef __attribute__((ext_vector_type(16))) float f32x16;
typedef __attribute__((ext_vector_type(4))) unsigned u32x4;
typedef __hip_bfloat16 bf16;

__device__ __forceinline__ void gload_lds16(const void* g, void* l) {
  __builtin_amdgcn_global_load_lds((const __attribute__((address_space(1))) void*)g,
                                   (__attribute__((address_space(3))) void*)l, 16, 0, 0);
}
__device__ __forceinline__ unsigned short f2bf_rne(float x) {
  unsigned u = __builtin_bit_cast(unsigned, x);
  u += 0x7FFFu + ((u >> 16) & 1u);
  return (unsigned short)(u >> 16);
}
__device__ __forceinline__ unsigned cvtpk_bf16(float lo, float hi) {
  unsigned w;
  asm("v_cvt_pk_bf16_f32 %0, %1, %2" : "=v"(w) : "v"(lo), "v"(hi));
  return w;
}

// ---------------------------------------------------------------------------
// Convert all 11 inputs (f32) to one contiguous bf16 region (verified R19).
// ---------------------------------------------------------------------------
__global__ __launch_bounds__(256)
void convert_all(const float* q, const float* k, const float* v,
                 const float* Wq, const float* bq, const float* Wk, const float* bk,
                 const float* Wv, const float* bv, const float* Wo, const float* bo,
                 bf16* __restrict__ dst)
{
  const int G = 3670528;
  for (int g = blockIdx.x * 256 + threadIdx.x; g < G; g += gridDim.x * 256) {
    const float* src; int lg;
    if      (g < 1048576) { src = q;  lg = g; }
    else if (g < 2097152) { src = k;  lg = g - 1048576; }
    else if (g < 3145728) { src = v;  lg = g - 2097152; }
    else if (g < 3276800) { src = Wq; lg = g - 3145728; }
    else if (g < 3407872) { src = Wk; lg = g - 3276800; }
    else if (g < 3538944) { src = Wv; lg = g - 3407872; }
    else if (g < 3670016) { src = Wo; lg = g - 3538944; }
    else if (g < 3670144) { src = bq; lg = g - 3670016; }
    else if (g < 3670272) { src = bk; lg = g - 3670144; }
    else if (g < 3670400) { src = bv; lg = g - 3670272; }
    else                  { src = bo; lg = g - 3670400; }
    const float4* s4 = ((const float4*)src) + (size_t)lg * 2;
    const float4 a = s4[0], b = s4[1];
    uint4 o;
    o.x = (unsigned)f2bf_rne(a.x) | ((unsigned)f2bf_rne(a.y) << 16);
    o.y = (unsigned)f2bf_rne(a.z) | ((unsigned)f2bf_rne(a.w) << 16);
    o.z = (unsigned)f2bf_rne(b.x) | ((unsigned)f2bf_rne(b.y) << 16);
    o.w = (unsigned)f2bf_rne(b.z) | ((unsigned)f2bf_rne(b.w) << 16);
    ((uint4*)dst)[g] = o;
  }
}

// ---------------------------------------------------------------------------
// MFMA GEMM (verified R19): out = A @ W.T + bias.
// MODE 0: bf16 [B,H,S,D] | MODE 1: bf16 [B,H,D,S] | MODE 2: f32 row-major.
// ---------------------------------------------------------------------------
template<int MODE>
__global__ __launch_bounds__(256, 2)
void gemm_bt(const bf16* __restrict__ A, const bf16* __restrict__ W,
             const bf16* __restrict__ bias, void* __restrict__ out)
{
  __shared__ char lds[32768];
  const int tid  = threadIdx.x;
  const int lane = tid & 63;
  const int wid  = tid >> 6;
  const int wr   = wid >> 1;
  const int wc   = wid & 1;
  const int bn   = blockIdx.x * 128;
  const int bm   = blockIdx.y * 128;

  f32x4 acc[4][4] = {};
  const char* Ab = (const char*)A;
  const char* Wb = (const char*)W;

  for (int k0 = 0; k0 < EMB; k0 += 64) {
    __syncthreads();
    #pragma unroll
    for (int r = 0; r < 4; ++r) {
      const int o   = r*4096 + wid*1024 + lane*16;
      const int row = o >> 7;
      const int cs  = (o & 127) ^ ((row & 7) << 4);
      gload_lds16(Ab + (size_t)(bm + row)*(EMB*2) + k0*2 + cs, lds + o);
      gload_lds16(Wb + (size_t)(bn + row)*(EMB*2) + k0*2 + cs, lds + 16384 + o);
    }
    __syncthreads();
    #pragma unroll
    for (int ks = 0; ks < 2; ++ks) {
      short8 af[4], bfr[4];
      const int d0 = ks*64 + ((lane >> 4) << 4);
      #pragma unroll
      for (int i = 0; i < 4; ++i) {
        const int ra = wr*64 + i*16 + (lane & 15);
        af[i]  = *(const short8*)(lds + ra*128 + (d0 ^ ((ra & 7) << 4)));
        const int rb = wc*64 + i*16 + (lane & 15);
        bfr[i] = *(const short8*)(lds + 16384 + rb*128 + (d0 ^ ((rb & 7) << 4)));
      }
      #pragma unroll
      for (int i = 0; i < 4; ++i)
        #pragma unroll
        for (int j = 0; j < 4; ++j)
          acc[i][j] = __builtin_amdgcn_mfma_f32_16x16x32_bf16(af[i], bfr[j], acc[i][j], 0, 0, 0);
    }
  }

  #pragma unroll
  for (int j = 0; j < 4; ++j) {
    const int n = bn + wc*64 + j*16 + (lane & 15);
    const float bv = __bfloat162float(bias[n]);
    #pragma unroll
    for (int i = 0; i < 4; ++i) {
      const int m0 = bm + wr*64 + i*16 + ((lane >> 4) << 2);
      if (MODE == 1) {
        const int b = m0 >> 11, s = m0 & 2047;
        const int h = n >> 6,  d = n & 63;
        ushort4 vv;
        #pragma unroll
        for (int r = 0; r < 4; ++r)
          ((unsigned short*)&vv)[r] = f2bf_rne(acc[i][j][r] + bv);
        *(ushort4*)((unsigned short*)out + ((size_t)((b*NH + h)*HD + d))*SEQ + s) = vv;
      } else if (MODE == 0) {
        #pragma unroll
        for (int r = 0; r < 4; ++r) {
          const int m = m0 + r;
          const int b = m >> 11, s = m & 2047;
          const int h = n >> 6,  d = n & 63;
          ((unsigned short*)out)[((size_t)((b*NH + h)*SEQ + s))*HD + d] = f2bf_rne(acc[i][j][r] + bv);
        }
      } else {
        #pragma unroll
        for (int r = 0; r < 4; ++r)
          ((float*)out)[(size_t)(m0 + r)*EMB + n] = acc[i][j][r] + bv;
      }
    }
  }
}

// ---------------------------------------------------------------------------
// 8-wave 32x32 flash attention (m214 structure, plain HIP).
// grid (SEQ/256, BS*NH), block 512. Per wave: 32 q-rows.
// Swapped QK^T (lane owns q-row), in-register softmax, cvt_pk+permlane32_swap
// P-pack, swapped PV with V^T from [B,H,D,S]. Output via LDS transpose.
// LDS: Q [0,32K) (dead after hoist, reused in epilogue) | K dbuf [32K,48K) |
//      V dbuf [48K,64K).
// ---------------------------------------------------------------------------
__global__ __launch_bounds__(512, 4)
void attn_fwd2(const bf16* __restrict__ Q, const bf16* __restrict__ Kt,
               const bf16* __restrict__ Vt, bf16* __restrict__ X)
{
  __shared__ char lds[65536];
  const int tid  = threadIdx.x;
  const int lane = tid & 63;
  const int wid  = tid >> 6;
  const int hi   = lane >> 5;
  const int ln31 = lane & 31;
  const int qt   = blockIdx.x;
  const int bh   = blockIdx.y;

  const char* Qg = (const char*)Q  + ((size_t)bh*SEQ + qt*256) * 128;
  const char* Kg = (const char*)Kt + ((size_t)bh*SEQ) * 128;
  const char* Vg = (const char*)Vt + ((size_t)bh*HD) * (SEQ*2);

  char* KB = lds + 32768;
  char* VB = lds + 49152;

  // stage Q (32KB) + K0/V0 (8KB each)
  #pragma unroll
  for (int j = 0; j < 4; ++j) {
    const int o = wid*4096 + j*1024 + lane*16;
    const int row = o >> 7, col = o & 127;
    gload_lds16(Qg + (size_t)row*128 + (col ^ ((row & 7) << 4)), lds + o);
  }
  {
    const int o = wid*1024 + lane*16;
    const int row = o >> 7, col = o & 127;
    const int cs = col ^ ((row & 7) << 4);
    gload_lds16(Kg + (size_t)row*128 + cs, KB + o);
    gload_lds16(Vg + (size_t)row*(SEQ*2) + cs, VB + o);
  }
  __syncthreads();

  // hoist Q B-frags (n=q=lane&31, k = ks*16 + hi*8 + j)
  short8 qf[4];
  {
    const int qr = wid*32 + ln31;
    #pragma unroll
    for (int ks = 0; ks < 4; ++ks)
      qf[ks] = *(const short8*)(lds + qr*128 + ((ks*32 + hi*16) ^ ((qr & 7) << 4)));
  }

  f32x16 O0 = {}, O1 = {};
  float m_run = -3.0e38f, l_run = 0.f;

  for (int t = 0; t < SEQ/64; ++t) {
    const int cur = t & 1;
    if (t + 1 < SEQ/64) {
      const int nxt = cur ^ 1;
      const int o = wid*1024 + lane*16;
      const int row = o >> 7, col = o & 127;
      const int cs = col ^ ((row & 7) << 4);
      gload_lds16(Kg + (size_t)((t+1)*64 + row)*128 + cs, KB + nxt*8192 + o);
      gload_lds16(Vg + (size_t)row*(SEQ*2) + (size_t)(t+1)*128 + cs, VB + nxt*8192 + o);
    }
    const char* KL = KB + cur*8192;
    const char* VL = VB + cur*8192;

    // S^T = K x Q^T : lane owns q=ln31; S0 = keys 0-31, S1 = keys 32-63
    f32x16 S0 = {}, S1 = {};
    #pragma unroll
    for (int ks = 0; ks < 4; ++ks) {
      const int cb = ks*32 + hi*16;
      const int r1 = 32 + ln31;
      short8 k0 = *(const short8*)(KL + ln31*128 + (cb ^ ((ln31 & 7) << 4)));
      short8 k1 = *(const short8*)(KL + r1*128   + (cb ^ ((r1 & 7) << 4)));
      S0 = __builtin_amdgcn_mfma_f32_32x32x16_bf16(k0, qf[ks], S0, 0, 0, 0);
      S1 = __builtin_amdgcn_mfma_f32_32x32x16_bf16(k1, qf[ks], S1, 0, 0, 0);
    }

    // scale + tile max (own 32 + partner half via lane^32)
    float mt = -3.0e38f;
    #pragma unroll
    for (int r = 0; r < 16; ++r) {
      S0[r] *= 0.125f; S1[r] *= 0.125f;
      mt = fmaxf(mt, fmaxf(S0[r], S1[r]));
    }
    mt = fmaxf(mt, __shfl_xor(mt, 32, 64));
    const float mn = fmaxf(m_run, mt);
    const float alpha = __expf(m_run - mn);
    m_run = mn;

    float ps = 0.f;
    #pragma unroll
    for (int r = 0; r < 16; ++r) {
      S0[r] = __expf(S0[r] - mn); ps += S0[r];
      S1[r] = __expf(S1[r] - mn); ps += S1[r];
    }
    ps += __shfl_xor(ps, 32, 64);
    l_run = l_run * alpha + ps;
    #pragma unroll
    for (int r = 0; r < 16; ++r) { O0[r] *= alpha; O1[r] *= alpha; }

    // pack P -> 4 B-frags (kk slots of 16), T12 recipe
    short8 pa[4];
    #pragma unroll
    for (int c = 0; c < 2; ++c) {
      const f32x16& S = c ? S1 : S0;
      #pragma unroll
      for (int f = 0; f < 2; ++f) {
        const int b0 = f*8;
        unsigned a0 = cvtpk_bf16(S[b0+0], S[b0+1]);
        unsigned b0w = cvtpk_bf16(S[b0+4], S[b0+5]);
        asm volatile("v_permlane32_swap_b32 %0, %1" : "+v"(a0), "+v"(b0w));
        unsigned a1 = cvtpk_bf16(S[b0+2], S[b0+3]);
        unsigned b1w = cvtpk_bf16(S[b0+6], S[b0+7]);
        asm volatile("v_permlane32_swap_b32 %0, %1" : "+v"(a1), "+v"(b1w));
        u32x4 w = {a0, a1, b0w, b1w};
        pa[c*2 + f] = __builtin_bit_cast(short8, w);
      }
    }

    // O^T += V^T x P^T : O0 = d 0-31, O1 = d 32-63 (q stays lane-local)
    #pragma unroll
    for (int slot = 0; slot < 4; ++slot) {
      const int cb = slot*32 + hi*16;
      const int r1 = 32 + ln31;
      short8 v0 = *(const short8*)(VL + ln31*128 + (cb ^ ((ln31 & 7) << 4)));
      short8 v1 = *(const short8*)(VL + r1*128   + (cb ^ ((r1 & 7) << 4)));
      O0 = __builtin_amdgcn_mfma_f32_32x32x16_bf16(v0, pa[slot], O0, 0, 0, 0);
      O1 = __builtin_amdgcn_mfma_f32_32x32x16_bf16(v1, pa[slot], O1, 0, 0, 0);
    }
    __syncthreads();
  }

  // epilogue: per-wave transpose through dead Q region, coalesced store
  __syncthreads();
  char* WR = lds + wid*4096;
  const float inv = 1.f / l_run;
  #pragma unroll
  for (int r = 0; r < 16; ++r) {
    const int d0 = (r & 3) + 8*(r >> 2) + 4*hi;
    *(unsigned short*)(WR + ln31*128 + ((2*d0) ^ ((ln31 & 7) << 4))) = f2bf_rne(O0[r] * inv);
    const int d1 = d0 + 32;
    *(unsigned short*)(WR + ln31*128 + ((2*d1) ^ ((ln31 & 7) << 4))) = f2bf_rne(O1[r] * inv);
  }
  asm volatile("s_waitcnt lgkmcnt(0)" ::: "memory");
  const int b = bh >> 4, h = bh & 15;
  #pragma unroll
  for (int pass = 0; pass < 4; ++pass) {
    const int row  = pass*8 + (lane >> 3);
    const int colb = ((lane & 7) * 16) ^ ((row & 7) << 4);
    short8 vv = *(const short8*)(WR + row*128 + colb);
    *(short8*)((unsigned short*)X + ((size_t)(b*SEQ) + qt*256 + wid*32 + row)*EMB
               + h*64 + (lane & 7)*8) = vv;
  }
}

// ---------------------------------------------------------------------------
extern "C" void kernel_launch(void* const* d_in, const int* in_sizes, int n_in,
                              void* d_out, int out_size, void* d_ws, size_t ws_size,
                              hipStream_t stream)
{
  const float* q  = (const float*)d_in[0];
  const float* k  = (const float*)d_in[1];
  const float* v  = (const float*)d_in[2];
  const float* Wq = (const float*)d_in[3];
  const float* bq = (const float*)d_in[4];
  const float* Wk = (const float*)d_in[5];
  const float* bk = (const float*)d_in[6];
  const float* Wv = (const float*)d_in[7];
  const float* bv = (const float*)d_in[8];
  const float* Wo = (const float*)d_in[9];
  const float* bo = (const float*)d_in[10];

  bf16* conv = (bf16*)d_ws;
  bf16* cq  = conv;
  bf16* ck  = conv + 8388608;
  bf16* cv  = conv + 16777216;
  bf16* cWq = conv + 25165824;
  bf16* cWk = cWq + 1048576;
  bf16* cWv = cWk + 1048576;
  bf16* cWo = cWv + 1048576;
  bf16* cbq = conv + 29360128;
  bf16* cbk = cbq + 1024;
  bf16* cbv = cbk + 1024;
  bf16* cbo = cbv + 1024;

  bf16* Qw = conv + 29364224;
  bf16* Kw = Qw + (size_t)MROWS*EMB;
  bf16* Vw = Kw + (size_t)MROWS*EMB;
  bf16* Xw = cq;                      // cq dead after Q-projection

  convert_all<<<2048, 256, 0, stream>>>(q, k, v, Wq, bq, Wk, bk, Wv, bv, Wo, bo, conv);

  dim3 gp(EMB/128, MROWS/128);   // (8, 64)
  gemm_bt<0><<<gp, 256, 0, stream>>>(cq, cWq, cbq, Qw);
  gemm_bt<0><<<gp, 256, 0, stream>>>(ck, cWk, cbk, Kw);
  gemm_bt<1><<<gp, 256, 0, stream>>>(cv, cWv, cbv, Vw);
  attn_fwd2<<<dim3(SEQ/256, BS*NH), 512, 0, stream>>>(Qw, Kw, Vw, Xw);
  gemm_bt<2><<<gp, 256, 0, stream>>>(Xw, cWo, cbo, (float*)d_out);
}